// Round 10
// baseline (767.613 us; speedup 1.0000x reference)
//
#include <hip/hip_runtime.h>
#include <math.h>

constexpr float DXC    = 3.125f;                              // 400/128
constexpr float INV_DX = 0.32f;                               // 1/3.125
constexpr float XMINC  = -200.0f;
constexpr float KW2    = 9.0f * 3.14159265358979323846f;      // cutoff^2 (mm^2)
constexpr float DXC2   = DXC * DXC;                           // 9.765625
constexpr float NEGL2C = -(2.0f / KW2) * 1.4426950408889634f * DXC2; // exp2 scale (cell^2)
constexpr float WOFF   = 1.7983f;                             // window anchor offset
constexpr float WMIN   = 0.13533528323661270f;                // e^-2: gate in product space

constexpr int TPB    = 1024;
constexpr int LPB    = 1024;   // LOR group per thread-slot
constexpr int LPT    = 2;      // LORs per thread
constexpr int KSPLIT = 8;
constexpr int KCH    = 128 / KSPLIT;
constexpr int QTAB   = 512;    // table bins over s in [0,4), float4

__device__ inline unsigned bf16_rn(float x) {
    unsigned u = __float_as_uint(x);
    return (u + 0x7fffu + ((u >> 16) & 1u)) >> 16;
}
__device__ inline unsigned pk_bf16(float x, float y) {
    return bf16_rn(x) | (bf16_rn(y) << 16);
}
__device__ inline float uaf(unsigned u) { return __uint_as_float(u); }

// ================= prep =================
// V0[k][i][j]=img[k][i][j]; V1[k][i][j]=img[i][k][j]; V2[k][i][j]=img[i][j][k]
__global__ __launch_bounds__(256) void prep_kernel(const float* __restrict__ img,
                                                   ushort* __restrict__ V0,
                                                   ushort* __restrict__ V1,
                                                   ushort* __restrict__ V2) {
    int o = blockIdx.x * 256 + threadIdx.x;
    float x = img[o];
    unsigned h = bf16_rn(x);
    V0[o] = (ushort)h;
    int c = o & 127, b = (o >> 7) & 127, a = o >> 14;
    V1[(b << 14) | (a << 7) | c] = (ushort)h;
    int j = o & 127, i = (o >> 7) & 127, k = o >> 14;
    V2[o] = (ushort)bf16_rn(img[(i << 14) | (j << 7) | k]);
}

__global__ __launch_bounds__(1024) void zero_kernel(float* __restrict__ out, int m) {
    int i = blockIdx.x * 1024 + threadIdx.x;
    if (i < m) out[i] = 0.0f;
}

// ================= staging: 32 KB bf16 slice, global->LDS DMA =================
__device__ inline void stage_one(const ushort* __restrict__ V, int k, int tid, void* dst) {
    const char* src = (const char*)(V + ((size_t)k << 14));
    char* d = (char*)dst;
    int wbase = (tid >> 6) << 10;
    int lane16 = (tid & 63) << 4;
#pragma unroll
    for (int c = 0; c < 2; ++c) {
        int half = c << 14;
        __builtin_amdgcn_global_load_lds(
            (__attribute__((address_space(1))) void*)(const_cast<char*>(src + half + wbase + lane16)),
            (__attribute__((address_space(3))) void*)(d + half + wbase),
            16, 0, 0);
    }
}

// ================= window state =================
struct WIN { float4 ea, eb; int rowdw, sh; };
struct LST { float u, v, cu, cv, path; };

template <int AXIS>
__device__ inline LST lor_setup(const float* __restrict__ lors, int lorc, int k0) {
    const float* l = lors + (size_t)lorc * 6;
    float l0 = l[0], l1 = l[1], l2 = l[2], l3 = l[3], l4 = l[4], l5 = l[5];
    float p0x, p0y, p0z, p1x, p1y, p1z;
    if (AXIS == 0)      { p0x = l1; p0y = l2; p0z = l0; p1x = l4; p1y = l5; p1z = l3; }
    else if (AXIS == 1) { p0x = l0; p0y = l2; p0z = l1; p1x = l3; p1y = l5; p1z = l4; }
    else                { p0x = l0; p0y = l1; p0z = l2; p1x = l3; p1y = l4; p1z = l5; }
    float dvx = p1x - p0x, dvy = p1y - p0y, dvz = p1z - p0z;
    float L     = sqrtf(dvx * dvx + dvy * dvy + dvz * dvz);
    float invdz = 1.0f / dvz;
    LST s;
    s.path = DXC * L / fabsf(dvz);
    float dux  = dvx * INV_DX, ux0 = (p0x - XMINC) * INV_DX;
    float dvyS = dvy * INV_DX, vy0 = (p0y - XMINC) * INV_DX;
    float tz0 = -p0z * invdz;
    float dt = DXC * invdz;
    s.cu = dux * dt; s.cv = dvyS * dt;
    float zc0 = fmaf((float)k0, DXC, XMINC + 0.5f * DXC);
    float t0  = fmaf(zc0, invdz, tz0);
    s.u = fmaf(t0, dux, ux0);
    s.v = fmaf(t0, dvyS, vy0);
    return s;
}

__device__ inline WIN mkwin(float u, float v, const float4* wt) {
    WIN w;
    float e0f = fminf(fmaxf(floorf(v - WOFF), 0.0f), 124.0f);
    float i0f = fminf(fmaxf(floorf(u - WOFF), 0.0f), 124.0f);
    int qv = min((int)((v - e0f) * (QTAB / 4.0f)), QTAB - 1);
    int qu = min((int)((u - i0f) * (QTAB / 4.0f)), QTAB - 1);
    w.eb = wt[qv];
    w.ea = wt[qu];
    int e0 = (int)e0f, i0 = (int)i0f;
    w.sh    = (e0 & 1) << 4;
    w.rowdw = (i0 << 6) + (e0 >> 1);
    return w;
}

// 4x4 taps: 3 dwords/row, alignbit funnel-extract, product-space gate
__device__ inline float do_slice(const WIN& w, const uint* __restrict__ sl, float acc) {
    float eaa[4] = {w.ea.x, w.ea.y, w.ea.z, w.ea.w};
#pragma unroll
    for (int r = 0; r < 4; ++r) {
        const uint* sr = sl + w.rowdw + (r << 6);
        uint d0 = sr[0], d1 = sr[1], d2 = sr[2];
        uint p01 = __builtin_amdgcn_alignbit(d1, d0, w.sh);
        uint p23 = __builtin_amdgcn_alignbit(d2, d1, w.sh);
        float x0 = uaf(p01 << 16), x1 = uaf(p01 & 0xffff0000u);
        float x2 = uaf(p23 << 16), x3 = uaf(p23 & 0xffff0000u);
        float er = eaa[r];
        float p0 = er * w.eb.x, p1 = er * w.eb.y, p2 = er * w.eb.z, p3 = er * w.eb.w;
        p0 = (p0 >= WMIN) ? p0 : 0.0f;
        p1 = (p1 >= WMIN) ? p1 : 0.0f;
        p2 = (p2 >= WMIN) ? p2 : 0.0f;
        p3 = (p3 >= WMIN) ? p3 : 0.0f;
        acc = fmaf(p0, x0, acc);
        acc = fmaf(p1, x1, acc);
        acc = fmaf(p2, x2, acc);
        acc = fmaf(p3, x3, acc);
    }
    return acc;
}

__device__ inline void fill_wtab(float4* wt, int tid) {
    if (tid < QTAB) {
        float s = ((float)tid + 0.5f) * (4.0f / (float)QTAB);
        float4 e;
        float o0 = 0.5f - s, o1 = 1.5f - s, o2 = 2.5f - s, o3 = 3.5f - s;
        e.x = exp2f(o0 * o0 * NEGL2C);
        e.y = exp2f(o1 * o1 * NEGL2C);
        e.z = exp2f(o2 * o2 * NEGL2C);
        e.w = exp2f(o3 * o3 * NEGL2C);
        wt[tid] = e;
    }
}

// ================= v10: dbuf + alignbit + product gate + 2 LOR/thread =================
template <int AXIS>
__device__ void proj_axis10(uint (*sl)[8192], float4* wt,
                            const ushort* __restrict__ V,
                            const float* __restrict__ lors,
                            float* __restrict__ out, int n, int blk, int ks)
{
    const int tid = threadIdx.x;
    int lor0 = blk * (LPT * LPB) + tid;
    int lor1 = lor0 + LPB;
    bool act0 = lor0 < n, act1 = lor1 < n;
    int lc0 = act0 ? lor0 : n - 1;
    int lc1 = act1 ? lor1 : n - 1;

    const int k0 = ks * KCH, k1 = k0 + KCH;
    LST s0 = lor_setup<AXIS>(lors, lc0, k0);
    LST s1 = lor_setup<AXIS>(lors, lc1, k0);
    float acc0 = 0.0f, acc1 = 0.0f;

    stage_one(V, k0, tid, sl[k0 & 1]);
    fill_wtab(wt, tid);
    __syncthreads();   // table ready AND slice k0 DMA drained

    WIN w0 = mkwin(s0.u, s0.v, wt);
    WIN w1 = mkwin(s1.u, s1.v, wt);

    for (int k = k0; k < k1; ++k) {
        const uint* sbuf = sl[k & 1];
        if (k < k1 - 1) stage_one(V, k + 1, tid, sl[(k & 1) ^ 1]);  // overlaps compute

        acc0 = do_slice(w0, sbuf, acc0);
        acc1 = do_slice(w1, sbuf, acc1);

        if (k < k1 - 1) {
            s0.u += s0.cu; s0.v += s0.cv;
            s1.u += s1.cu; s1.v += s1.cv;
            w0 = mkwin(s0.u, s0.v, wt);
            w1 = mkwin(s1.u, s1.v, wt);
            __syncthreads();               // drains DMA -> slice k+1 ready
        }
    }

    if (act0) atomicAdd(out + lor0, acc0 * s0.path);
    if (act1) atomicAdd(out + lor1, acc1 * s1.path);
}

__global__ __launch_bounds__(TPB, 8) void proj_fused10(const ushort* __restrict__ V0,
                                                       const ushort* __restrict__ V1,
                                                       const ushort* __restrict__ V2,
                                                       const float* __restrict__ xl,
                                                       const float* __restrict__ yl,
                                                       const float* __restrict__ zl,
                                                       float* __restrict__ out,
                                                       int n, int nblk)
{
    __shared__ uint   sl[2][8192];   // 64 KiB double-buffered bf16 slice
    __shared__ float4 wt[QTAB];      // 8 KiB weight table
    int per = nblk * KSPLIT;
    int axis = blockIdx.x / per;
    int r = blockIdx.x - axis * per;
    int blk = r >> 3;                // KSPLIT = 8
    int ks  = r & 7;
    if (axis == 0)      proj_axis10<0>(sl, wt, V0, xl, out, n, blk, ks);
    else if (axis == 1) proj_axis10<1>(sl, wt, V1, yl, out + n, n, blk, ks);
    else                proj_axis10<2>(sl, wt, V2, zl, out + 2 * (size_t)n, n, blk, ks);
}

// ================= fallback (no/partial ws): reg-staged, 1 LOR/thread =================
template <int AXIS>
__device__ inline void stage_issue(const float* __restrict__ img, int k, int tid,
                                   float4 st[4]) {
#pragma unroll
    for (int c = 0; c < 4; ++c) {
        int f4 = tid + TPB * c;
        int fl = f4 << 2;
        if (AXIS == 2) {
            int i = fl >> 7, j = fl & 127;
            const float* p = img + (i << 14) + (j << 7) + k;
            st[c] = make_float4(p[0], p[128], p[256], p[384]);
        } else {
            int off;
            if (AXIS == 1) off = ((fl >> 7) << 14) | (k << 7) | (fl & 127);
            else           off = (k << 14) | fl;
            st[c] = *reinterpret_cast<const float4*>(img + off);
        }
    }
}

__device__ inline void stage_write(const float4 st[4], uint* slb, int tid) {
#pragma unroll
    for (int c = 0; c < 4; ++c) {
        int f4 = tid + TPB * c;
        slb[f4 * 2]     = pk_bf16(st[c].x, st[c].y);
        slb[f4 * 2 + 1] = pk_bf16(st[c].z, st[c].w);
    }
}

template <int AXIS, bool PRE>
__device__ void proj_axis7(uint (*sl)[8192], float4* wtab,
                           const ushort* __restrict__ V,
                           const float*  __restrict__ imgF,
                           const float*  __restrict__ lors,
                           float* __restrict__ out, int n, int blk, int ks)
{
    const int tid = threadIdx.x;
    const int lor = blk * LPB + tid;
    const bool active = lor < n;
    const int lorc = active ? lor : n - 1;

    const int k0 = ks * KCH, k1 = k0 + KCH;
    LST s = lor_setup<AXIS>(lors, lorc, k0);
    float acc = 0.0f;

    if (PRE) {
        stage_one(V, k0, tid, sl[k0 & 1]);
    } else {
        float4 st[4];
        stage_issue<AXIS>(imgF, k0, tid, st);
        stage_write(st, sl[k0 & 1], tid);
    }
    fill_wtab(wtab, tid);
    __syncthreads();

    WIN w = mkwin(s.u, s.v, wtab);

    for (int k = k0; k < k1; ++k) {
        const uint* sbuf = sl[k & 1];
        float4 st2[4];
        if (k < k1 - 1) {
            if (PRE) stage_one(V, k + 1, tid, sl[(k & 1) ^ 1]);
            else     stage_issue<AXIS>(imgF, k + 1, tid, st2);
        }

        acc = do_slice(w, sbuf, acc);

        if (k < k1 - 1) {
            s.u += s.cu; s.v += s.cv;
            w = mkwin(s.u, s.v, wtab);
            if (!PRE) stage_write(st2, sl[(k & 1) ^ 1], tid);
            __syncthreads();
        }
    }

    if (active) atomicAdd(out + lor, acc * s.path);
}

template <bool PRE>
__global__ __launch_bounds__(TPB, 8) void proj_fused7(const float* __restrict__ img,
                                                      const ushort* __restrict__ V0,
                                                      const ushort* __restrict__ V1,
                                                      const ushort* __restrict__ V2,
                                                      const float* __restrict__ xl,
                                                      const float* __restrict__ yl,
                                                      const float* __restrict__ zl,
                                                      float* __restrict__ out,
                                                      int n, int nblk)
{
    __shared__ uint   sl[2][8192];
    __shared__ float4 wtab[QTAB];
    int per = nblk * KSPLIT;
    int axis = blockIdx.x / per;
    int r = blockIdx.x - axis * per;
    int blk = r >> 3;
    int ks  = r & 7;
    if (axis == 0)      proj_axis7<0, PRE>(sl, wtab, V0, img, xl, out, n, blk, ks);
    else if (axis == 1) proj_axis7<1, PRE>(sl, wtab, V1, img, yl, out + n, n, blk, ks);
    else                proj_axis7<2, PRE>(sl, wtab, V2, img, zl, out + 2 * (size_t)n, n, blk, ks);
}

extern "C" void kernel_launch(void* const* d_in, const int* in_sizes, int n_in,
                              void* d_out, int out_size, void* d_ws, size_t ws_size,
                              hipStream_t stream) {
    const float* img   = (const float*)d_in[0];
    const float* xlors = (const float*)d_in[1];
    const float* ylors = (const float*)d_in[2];
    const float* zlors = (const float*)d_in[3];
    float* out = (float*)d_out;

    int n = in_sizes[1] / 6;
    int m = 3 * n;

    zero_kernel<<<(m + 1023) / 1024, 1024, 0, stream>>>(out, m);

    constexpr size_t VOL = 128 * 128 * 128;

    if (ws_size >= 3 * VOL * sizeof(ushort)) {
        int nblk = (n + LPT * LPB - 1) / (LPT * LPB);
        int grid = 3 * nblk * KSPLIT;
        ushort* V0 = (ushort*)d_ws;
        ushort* V1 = V0 + VOL;  ushort* V2 = V1 + VOL;
        prep_kernel<<<VOL / 256, 256, 0, stream>>>(img, V0, V1, V2);
        proj_fused10<<<grid, TPB, 0, stream>>>(V0, V1, V2,
                                               xlors, ylors, zlors, out, n, nblk);
    } else {
        int nblk = (n + LPB - 1) / LPB;
        int grid = 3 * nblk * KSPLIT;
        proj_fused7<false><<<grid, TPB, 0, stream>>>(img, nullptr, nullptr, nullptr,
                                                     xlors, ylors, zlors, out, n, nblk);
    }
}

// Round 11
// 312.270 us; speedup vs baseline: 2.4582x; 2.4582x over previous
//
#include <hip/hip_runtime.h>
#include <math.h>

constexpr float DXC    = 3.125f;                              // 400/128
constexpr float INV_DX = 0.32f;                               // 1/3.125
constexpr float XMINC  = -200.0f;
constexpr float KW2    = 9.0f * 3.14159265358979323846f;      // cutoff^2 (mm^2)
constexpr float DXC2   = DXC * DXC;                           // 9.765625
constexpr float KW2C   = KW2 / DXC2;                          // cutoff^2 in cell^2
constexpr float NEGL2C = -(2.0f / KW2) * 1.4426950408889634f * DXC2; // exp2 scale (cell^2)
constexpr float WOFF   = 1.7983f;                             // window anchor offset

constexpr int TPB    = 1024;   // threads per block = LORs per block
constexpr int LPB    = 1024;
constexpr int KSPLIT = 8;      // k-range split across blocks (R7 had 4; R9 proved 8 safe)
constexpr int KCH    = 128 / KSPLIT;
constexpr int QTAB   = 1024;   // weight-table bins over s in [0,4)

__device__ inline unsigned bf16_rn(float x) {
    unsigned u = __float_as_uint(x);
    return (u + 0x7fffu + ((u >> 16) & 1u)) >> 16;
}
__device__ inline unsigned pk_bf16(float x, float y) {
    return bf16_rn(x) | (bf16_rn(y) << 16);
}
__device__ inline float uaf(unsigned u) { return __uint_as_float(u); }

// ---- prep: bf16 volumes, slice-contiguous [k][i][j] layouts per axis
__global__ __launch_bounds__(256) void prep_kernel(const float* __restrict__ img,
                                                   ushort* __restrict__ V0,
                                                   ushort* __restrict__ V1,
                                                   ushort* __restrict__ V2) {
    int o = blockIdx.x * 256 + threadIdx.x;
    float x = img[o];
    unsigned h = bf16_rn(x);
    V0[o] = (ushort)h;
    int c = o & 127, b = (o >> 7) & 127, a = o >> 14;
    V1[(b << 14) | (a << 7) | c] = (ushort)h;
    int j = o & 127, i = (o >> 7) & 127, k = o >> 14;
    V2[o] = (ushort)bf16_rn(img[(i << 14) | (j << 7) | k]);
}

__global__ __launch_bounds__(1024) void zero_kernel(float* __restrict__ out, int m) {
    int i = blockIdx.x * 1024 + threadIdx.x;
    if (i < m) out[i] = 0.0f;
}

// ---- staging: 32KB bf16 slice global->LDS DMA (R7-exact)
__device__ inline void stage_one(const ushort* __restrict__ V, int k, int tid, void* dst) {
    const char* src = (const char*)(V + ((size_t)k << 14));
    char* d = (char*)dst;
    int wbase = (tid >> 6) << 10;           // wave * 1024 bytes
    int lane16 = (tid & 63) << 4;
#pragma unroll
    for (int c = 0; c < 2; ++c) {
        int half = c << 14;                 // 0 / 16384
        __builtin_amdgcn_global_load_lds(
            (__attribute__((address_space(1))) void*)(const_cast<char*>(src + half + wbase + lane16)),
            (__attribute__((address_space(3))) void*)(d + half + wbase),
            16, 0, 0);
    }
}

// Fallback staging (no ws): fp32 global -> regs -> convert -> LDS
template <int AXIS>
__device__ inline void stage_issue(const float* __restrict__ img, int k, int tid,
                                   float4 st[4]) {
#pragma unroll
    for (int c = 0; c < 4; ++c) {
        int f4 = tid + TPB * c;
        int fl = f4 << 2;
        if (AXIS == 2) {
            int i = fl >> 7, j = fl & 127;
            const float* p = img + (i << 14) + (j << 7) + k;
            st[c] = make_float4(p[0], p[128], p[256], p[384]);
        } else {
            int off;
            if (AXIS == 1) off = ((fl >> 7) << 14) | (k << 7) | (fl & 127);
            else           off = (k << 14) | fl;
            st[c] = *reinterpret_cast<const float4*>(img + off);
        }
    }
}

__device__ inline void stage_write(const float4 st[4], ushort* slb, int tid) {
    uint* w = reinterpret_cast<uint*>(slb);
#pragma unroll
    for (int c = 0; c < 4; ++c) {
        int f4 = tid + TPB * c;
        w[f4 * 2]     = pk_bf16(st[c].x, st[c].y);
        w[f4 * 2 + 1] = pk_bf16(st[c].z, st[c].w);
    }
}

template <int AXIS, bool PRE>
__device__ void proj_axis(ushort (*sl)[16384], float4* wtab,
                          const ushort* __restrict__ V,
                          const float*  __restrict__ imgF,
                          const float*  __restrict__ lors,
                          float* __restrict__ out, int n, int blk, int ks)
{
    const int tid = threadIdx.x;
    const int lor = blk * LPB + tid;
    const bool active = lor < n;
    const int lorc = active ? lor : n - 1;

    const float* l = lors + (size_t)lorc * 6;
    float l0 = l[0], l1 = l[1], l2 = l[2], l3 = l[3], l4 = l[4], l5 = l[5];
    float p0x, p0y, p0z, p1x, p1y, p1z;
    if (AXIS == 0)      { p0x = l1; p0y = l2; p0z = l0; p1x = l4; p1y = l5; p1z = l3; }
    else if (AXIS == 1) { p0x = l0; p0y = l2; p0z = l1; p1x = l3; p1y = l5; p1z = l4; }
    else                { p0x = l0; p0y = l1; p0z = l2; p1x = l3; p1y = l4; p1z = l5; }

    float dvx = p1x - p0x, dvy = p1y - p0y, dvz = p1z - p0z;
    float L     = sqrtf(dvx * dvx + dvy * dvy + dvz * dvz);
    float pathL = DXC * L / fabsf(dvz);
    float invdz = 1.0f / dvz;

    // u(k), v(k) affine in k -> incremental
    float dux  = dvx * INV_DX, ux0 = (p0x - XMINC) * INV_DX;
    float dvyS = dvy * INV_DX, vy0 = (p0y - XMINC) * INV_DX;
    float tzs = invdz, tz0 = -p0z * invdz;
    // t in [0,1] vacuous: per-axis LOR endpoints sit on the +-half faces.

    const int k0 = ks * KCH, k1 = k0 + KCH;

    float dt = DXC * tzs;
    float cu = dux * dt, cv = dvyS * dt;
    float zc0 = fmaf((float)k0, DXC, XMINC + 0.5f * DXC);
    float t0  = fmaf(zc0, tzs, tz0);
    float u   = fmaf(t0, dux, ux0);
    float v   = fmaf(t0, dvyS, vy0);
    float acc = 0.0f;

    // prologue: issue slice-k0 staging, fill weight table under it
    if (PRE) {
        stage_one(V, k0, tid, sl[k0 & 1]);
    } else {
        float4 st[4];
        stage_issue<AXIS>(imgF, k0, tid, st);
        stage_write(st, sl[k0 & 1], tid);
    }
    {   // wtab[q] = 4-row weights at sub-window offset s=(q+0.5)*4/QTAB
        float s = ((float)tid + 0.5f) * (4.0f / (float)QTAB);
        float4 e;
        float o0 = 0.5f - s, o1 = 1.5f - s, o2 = 2.5f - s, o3 = 3.5f - s;
        e.x = exp2f(o0 * o0 * NEGL2C);
        e.y = exp2f(o1 * o1 * NEGL2C);
        e.z = exp2f(o2 * o2 * NEGL2C);
        e.w = exp2f(o3 * o3 * NEGL2C);
        wtab[tid] = e;
    }
    __syncthreads();

    for (int k = k0; k < k1; ++k) {
        const ushort* sbuf = sl[k & 1];
        float4 st2[4];
        if (k < k1 - 1) {                       // issue next-slice loads early (dbuf)
            if (PRE) stage_one(V, k + 1, tid, sl[(k & 1) ^ 1]);
            else     stage_issue<AXIS>(imgF, k + 1, tid, st2);
        }

        // ---- column (j): clamp via med3; s in [0,4) so q needs no clamp
        float e0f = __builtin_amdgcn_fmed3f(floorf(v - WOFF), 0.0f, 124.0f);
        int   e0  = (int)e0f;
        int   qv  = (int)((v - e0f) * (QTAB / 4.0f));
        float4 eb = wtab[qv];
        float db0 = e0f + 0.5f - v;
        float b0 = db0 * db0;
        float gb = fmaf(2.0f, db0, 1.0f);
        float b1 = b0 + gb, gb1 = gb + 2.0f;
        float b2 = b1 + gb1, gb2 = gb1 + 2.0f;
        float b3 = b2 + gb2;

        // ---- row (i)
        float i0f = __builtin_amdgcn_fmed3f(floorf(u - WOFF), 0.0f, 124.0f);
        int   i0c = (int)i0f;
        int   qu  = (int)((u - i0f) * (QTAB / 4.0f));
        float4 ea = wtab[qu];
        float da0 = i0f + 0.5f - u;
        float a0 = da0 * da0;
        float ga = fmaf(2.0f, da0, 1.0f);
        float a1 = a0 + ga, ga1 = ga + 2.0f;
        float a2 = a1 + ga1, ga2 = ga1 + 2.0f;
        float a3 = a2 + ga2;
        float thr[4] = {KW2C - a0, KW2C - a1, KW2C - a2, KW2C - a3};
        float eaa[4] = {ea.x, ea.y, ea.z, ea.w};

        // ---- gather 4x4: 3 dwords/row, alignbit funnel-extract 4 bf16
        const uint* s32 = reinterpret_cast<const uint*>(sbuf);
        int dwc = e0 >> 1;
        int sh  = (e0 & 1) << 4;
        int rowdw = (i0c << 6) + dwc;
#pragma unroll
        for (int r = 0; r < 4; ++r) {
            const uint* sr = s32 + rowdw + (r << 6);
            uint d0 = sr[0], d1 = sr[1], d2 = sr[2];
            uint p01 = __builtin_amdgcn_alignbit(d1, d0, sh);
            uint p23 = __builtin_amdgcn_alignbit(d2, d1, sh);
            float w0 = uaf(p01 << 16);
            float w1 = uaf(p01 & 0xffff0000u);
            float w2 = uaf(p23 << 16);
            float w3 = uaf(p23 & 0xffff0000u);
            float tr = thr[r];
            float rs;
            rs = __fmul_rn((b0 <= tr) ? eb.x : 0.0f, w0);
            rs = fmaf((b1 <= tr) ? eb.y : 0.0f, w1, rs);
            rs = fmaf((b2 <= tr) ? eb.z : 0.0f, w2, rs);
            rs = fmaf((b3 <= tr) ? eb.w : 0.0f, w3, rs);
            acc = fmaf(eaa[r], rs, acc);
        }

        u += cu; v += cv;

        if (k < k1 - 1) {
            if (!PRE) stage_write(st2, sl[(k & 1) ^ 1], tid);
            __syncthreads();                    // drains DMA -> slice k+1 ready
        }
    }

    if (active) atomicAdd(out + lor, acc * pathL);
}

template <bool PRE>
__global__ __launch_bounds__(TPB, 8) void proj_fused(const float* __restrict__ img,
                                                     const ushort* __restrict__ V0,
                                                     const ushort* __restrict__ V1,
                                                     const ushort* __restrict__ V2,
                                                     const float* __restrict__ xl,
                                                     const float* __restrict__ yl,
                                                     const float* __restrict__ zl,
                                                     float* __restrict__ out,
                                                     int n, int nblk)
{
    __shared__ ushort sl[2][16384];   // 64 KiB double-buffered bf16 slice
    __shared__ float4 wtab[QTAB];     // 16 KiB weight table
    int per = nblk * KSPLIT;
    int axis = blockIdx.x / per;
    int r = blockIdx.x - axis * per;
    int blk = r >> 3;                 // KSPLIT = 8
    int ks  = r & 7;
    if (axis == 0)      proj_axis<0, PRE>(sl, wtab, V0, img, xl, out, n, blk, ks);
    else if (axis == 1) proj_axis<1, PRE>(sl, wtab, V1, img, yl, out + n, n, blk, ks);
    else                proj_axis<2, PRE>(sl, wtab, V2, img, zl, out + 2 * (size_t)n, n, blk, ks);
}

extern "C" void kernel_launch(void* const* d_in, const int* in_sizes, int n_in,
                              void* d_out, int out_size, void* d_ws, size_t ws_size,
                              hipStream_t stream) {
    const float* img   = (const float*)d_in[0];
    const float* xlors = (const float*)d_in[1];
    const float* ylors = (const float*)d_in[2];
    const float* zlors = (const float*)d_in[3];
    float* out = (float*)d_out;

    int n = in_sizes[1] / 6;
    int nblk = (n + LPB - 1) / LPB;
    int m = 3 * n;

    zero_kernel<<<(m + 1023) / 1024, 1024, 0, stream>>>(out, m);

    constexpr size_t VOL = 128 * 128 * 128;
    bool pre = ws_size >= 3 * VOL * sizeof(ushort);
    int grid = 3 * nblk * KSPLIT;

    if (pre) {
        ushort* V0 = (ushort*)d_ws;
        ushort* V1 = V0 + VOL;
        ushort* V2 = V1 + VOL;
        prep_kernel<<<VOL / 256, 256, 0, stream>>>(img, V0, V1, V2);
        proj_fused<true><<<grid, TPB, 0, stream>>>(img, V0, V1, V2,
                                                   xlors, ylors, zlors, out, n, nblk);
    } else {
        proj_fused<false><<<grid, TPB, 0, stream>>>(img, nullptr, nullptr, nullptr,
                                                    xlors, ylors, zlors, out, n, nblk);
    }
}